// Round 8
// baseline (19689.452 us; speedup 1.0000x reference)
//
#include <hip/hip_runtime.h>
#include <math.h>

// ---------------------------------------------------------------------------
// CurvePredictor R8: global_load_lds double-buffered weight streaming.
// 64 blocks x 512 threads (8 waves), 32 batch rows/block, weights L2-resident
// (proven R7). R7's remaining 20us/step was exposed L2 latency: VGPR batches
// were serialized by the register allocator (VGPR stuck at 128). Fix: stream
// weights via async LDS-DMA (zero VGPR cost, depth structural): per 4KB round,
// issue next round's 4 DMAs, s_waitcnt vmcnt(4), ds_read_b128 current buffer,
// 8 MFMAs. Swizzled layout == DMA addressing model (base + lane*16).
// Double-buffered h0/h1 in LDS, 3 barriers/step, zero cross-block sync.
// ---------------------------------------------------------------------------

typedef short s8v __attribute__((ext_vector_type(8)));   // 8 x bf16
typedef float f4v __attribute__((ext_vector_type(4)));   // 4 x f32

#define HSTR 264            // LDS h-row stride in shorts (33*16B)
#define DSTR 136

// s_waitcnt simm16: vmcnt lo[3:0], expcnt[6:4], lgkmcnt[11:8], vmcnt hi[15:14]
#define S_WAIT_LGKM0() __builtin_amdgcn_s_waitcnt(0xC07F)  // lgkmcnt(0) only
#define S_WAIT_VM4()   __builtin_amdgcn_s_waitcnt(0x0F74)  // vmcnt(4) only
#define S_WAIT_VM0()   __builtin_amdgcn_s_waitcnt(0x0F70)  // vmcnt(0) only

__device__ __forceinline__ f4v mfma16(s8v a, s8v b, f4v c){
  return __builtin_amdgcn_mfma_f32_16x16x32_bf16(a, b, c, 0, 0, 0);
}
__device__ __forceinline__ void dma16(const short* g, short* l){
  __builtin_amdgcn_global_load_lds(
      (const __attribute__((address_space(1))) void*)g,
      (__attribute__((address_space(3))) void*)l, 16, 0, 0);
}
__device__ __forceinline__ short f2bf(float f){
  unsigned u = __float_as_uint(f);
  u = u + 0x7FFFu + ((u >> 16) & 1u);
  return (short)(u >> 16);
}
__device__ __forceinline__ float wred(float v){
  #pragma unroll
  for (int o = 32; o; o >>= 1) v += __shfl_xor(v, o);
  return v;
}
__device__ __forceinline__ float sigm(float x){ return 1.0f / (1.0f + __expf(-x)); }
__device__ __forceinline__ float tnh(float x){
  x = fminf(15.0f, fmaxf(-15.0f, x));
  float e = __expf(2.0f * x);
  return (e - 1.0f) / (e + 1.0f);
}
__device__ __forceinline__ float gelu(float v){
  return 0.5f * v * (1.0f + erff(v * 0.70710678118654752440f));
}

// ws layout (shorts), swizzled for coalesced/DMA B-frag loads (same as R5-R7):
// main matrices (1024x256): elem = s*16384 + g*4096 + kk*512 + lane*8 + j
//   lane = q*16+m16, hid = s*16+m16, k = kk*32+q*8+j, gate-row = g*256+hid
//   [0,262144) Wih0  [262144,524288) Whh0  [524288,786432) Wih1  [786432,1048576) Whh1
// W3 [128][256]: 1048576 + s2*4096 + kk*512 + lane*8  (row = s2*16+m16)
// W4 padded [16][128]: 1081344 + kk*512 + lane*8      (row = m16, kk<4)
__global__ void prep_kernel(
    const float* __restrict__ Wih0, const float* __restrict__ Whh0,
    const float* __restrict__ Wih1, const float* __restrict__ Whh1,
    const float* __restrict__ W3,   const float* __restrict__ W4,
    short* __restrict__ wsb)
{
  const int i = blockIdx.x * 256 + threadIdx.x;
  if (i >= 1083392) return;
  float v;
  if (i < 1048576){
    const int seg = i >> 18;
    const int r   = i & 262143;
    const int s   = r >> 14;
    const int g   = (r >> 12) & 3;
    const int kk  = (r >> 9) & 7;
    const int q   = (r >> 7) & 3;
    const int m16 = (r >> 3) & 15;
    const int j   = r & 7;
    const int hid = s * 16 + m16;
    const int k   = kk * 32 + q * 8 + j;
    const float* mt = (seg == 0) ? Wih0 : (seg == 1) ? Whh0 : (seg == 2) ? Wih1 : Whh1;
    v = mt[(g * 256 + hid) * 256 + k];
  } else if (i < 1081344){
    const int r   = i - 1048576;
    const int s2  = r >> 12;
    const int kk  = (r >> 9) & 7;
    const int q   = (r >> 7) & 3;
    const int m16 = (r >> 3) & 15;
    const int j   = r & 7;
    v = W3[(s2 * 16 + m16) * 256 + kk * 32 + q * 8 + j];
  } else {
    const int r   = i - 1081344;
    const int kk  = (r >> 9) & 3;
    const int q   = (r >> 7) & 3;
    const int m16 = (r >> 3) & 15;
    const int j   = r & 7;
    const int k   = kk * 32 + q * 8 + j;
    v = (m16 < 2) ? W4[m16 * 128 + k] : 0.0f;
  }
  wsb[i] = f2bf(v);
}

__global__ __launch_bounds__(512, 1) void curve_main(
    const float* __restrict__ x,
    const float* __restrict__ W1, const float* __restrict__ b1,
    const float* __restrict__ g1, const float* __restrict__ be1,
    const float* __restrict__ W2, const float* __restrict__ b2,
    const float* __restrict__ g2, const float* __restrict__ be2,
    const float* __restrict__ bih0, const float* __restrict__ bhh0,
    const float* __restrict__ bih1, const float* __restrict__ bhh1,
    const float* __restrict__ b3, const float* __restrict__ b4,
    const short* __restrict__ wsb,
    float* __restrict__ out)
{
  const int tid  = threadIdx.x;
  const int w    = tid >> 6;        // wave 0..7 <-> 32-col hidden slice
  const int lane = tid & 63;
  const int q    = lane >> 4;
  const int m16  = lane & 15;
  const int row0 = blockIdx.x * 32;

  __shared__ __align__(16) short h0b[2][32 * HSTR];
  __shared__ __align__(16) short h1b[2][32 * HSTR];
  __shared__ __align__(16) short dstg[32 * DSTR];
  __shared__ __align__(16) short wst[8 * 4096];    // 8 waves x 2 bufs x 4KB

  // --------- encoder: wave w computes batch rows row0 + u*8 + w ------------
  #pragma unroll 1
  for (int u = 0; u < 4; u++){
    const int rr = u * 8 + w;
    const int r  = row0 + rr;
    float xv[5];
    #pragma unroll
    for (int k = 0; k < 5; k++) xv[k] = x[r * 5 + k];
    float a0 = b1[lane], a1 = b1[lane + 64];
    #pragma unroll
    for (int k = 0; k < 5; k++){
      a0 += xv[k] * W1[lane * 5 + k];
      a1 += xv[k] * W1[(lane + 64) * 5 + k];
    }
    a0 = gelu(a0); a1 = gelu(a1);
    float mean = wred(a0 + a1) * (1.0f / 128.0f);
    float d0 = a0 - mean, d1 = a1 - mean;
    float inv = rsqrtf(wred(d0 * d0 + d1 * d1) * (1.0f / 128.0f) + 1e-5f);
    float y0 = d0 * inv * g1[lane]      + be1[lane];
    float y1 = d1 * inv * g1[lane + 64] + be1[lane + 64];

    float acc2[4];
    #pragma unroll
    for (int uu = 0; uu < 4; uu++) acc2[uu] = b2[lane + 64 * uu];
    for (int k = 0; k < 64; k++){
      float v0 = __shfl(y0, k);
      float v1 = __shfl(y1, k);
      #pragma unroll
      for (int uu = 0; uu < 4; uu++){
        const float* wr = W2 + (lane + 64 * uu) * 128;
        acc2[uu] += v0 * wr[k] + v1 * wr[k + 64];
      }
    }
    #pragma unroll
    for (int uu = 0; uu < 4; uu++) acc2[uu] = gelu(acc2[uu]);
    float s = acc2[0] + acc2[1] + acc2[2] + acc2[3];
    mean = wred(s) * (1.0f / 256.0f);
    float vv = 0.0f;
    #pragma unroll
    for (int uu = 0; uu < 4; uu++){ float d = acc2[uu] - mean; vv += d * d; }
    inv = rsqrtf(wred(vv) * (1.0f / 256.0f) + 1e-5f);
    #pragma unroll
    for (int uu = 0; uu < 4; uu++){
      int c = lane + 64 * uu;
      float e = (acc2[uu] - mean) * inv * g2[c] + be2[c];
      h0b[0][rr * HSTR + c] = f2bf(e);       // enc staged in h0 slot 0
    }
  }
  __syncthreads();

  // swizzled slice bases (include per-lane offset lane*16B)
  const short* pwi0 = wsb            + (2 * w) * 16384 + (lane << 3);
  const short* pwh0 = wsb +  262144  + (2 * w) * 16384 + (lane << 3);
  const short* pwi1 = wsb +  524288  + (2 * w) * 16384 + (lane << 3);
  const short* pwh1 = wsb +  786432  + (2 * w) * 16384 + (lane << 3);
  const short* pw3  = wsb + 1048576  + w * 4096 + (lane << 3);
  const short* pw4  = wsb + 1081344  + (lane << 3);
  short* wstW = wst + (w << 12);    // this wave's 8KB staging (2 x 4KB bufs)

  // ---- xp0 = enc @ Wih0_slice^T + (bih0+bhh0), kept in registers ----
  f4v xp[2][2][4];                  // [ct][rt][gate]
  #pragma unroll
  for (int ct = 0; ct < 2; ct++)
    #pragma unroll
    for (int g = 0; g < 4; g++){
      const int n = g * 256 + w * 32 + ct * 16 + m16;
      const float bi = bih0[n] + bhh0[n];
      f4v t = {bi, bi, bi, bi};
      xp[ct][0][g] = t; xp[ct][1][g] = t;
    }
  #pragma unroll
  for (int ct = 0; ct < 2; ct++)
    #pragma unroll
    for (int kk = 0; kk < 8; kk++){
      const s8v a0 = *(const s8v*)&h0b[0][ m16       * HSTR + kk * 32 + q * 8];
      const s8v a1 = *(const s8v*)&h0b[0][(16 + m16) * HSTR + kk * 32 + q * 8];
      #pragma unroll
      for (int g = 0; g < 4; g++){
        const s8v B = *(const s8v*)(pwi0 + ct * 16384 + g * 4096 + kk * 512);
        xp[ct][0][g] = mfma16(a0, B, xp[ct][0][g]);
        xp[ct][1][g] = mfma16(a1, B, xp[ct][1][g]);
      }
    }
  __syncthreads();
  for (int i = tid; i < 32 * HSTR; i += 512){ h0b[0][i] = 0; h1b[0][i] = 0; }

  float bs1[2][4];
  #pragma unroll
  for (int ct = 0; ct < 2; ct++)
    #pragma unroll
    for (int g = 0; g < 4; g++){
      const int n = g * 256 + w * 32 + ct * 16 + m16;
      bs1[ct][g] = bih1[n] + bhh1[n];
    }
  const float b3c = b3[w * 16 + m16];
  const float b4v = (m16 < 2) ? b4[m16] : 0.0f;
  float c0[2][2][4], c1[2][2][4];   // [ct][rt][r]
  #pragma unroll
  for (int ct = 0; ct < 2; ct++)
    #pragma unroll
    for (int rt = 0; rt < 2; rt++)
      #pragma unroll
      for (int r = 0; r < 4; r++){ c0[ct][rt][r] = 0.f; c1[ct][rt][r] = 0.f; }
  __syncthreads();

  // --------------------------- recurrence over T ---------------------------
  #pragma unroll 1
  for (int t = 0; t < 256; t++){
    const short* h0in  = h0b[t & 1];
    short*       h0out = h0b[(t + 1) & 1];
    const short* h1in  = h1b[t & 1];
    short*       h1out = h1b[(t + 1) & 1];

    // ---- Phase A: gates0 = xp0 + h0_old @ Whh0^T (16 DMA rounds) ----
    {
      S_WAIT_LGKM0();
      dma16(pwh0,          wstW);
      dma16(pwh0 +  4096,  wstW +  512);
      dma16(pwh0 +  8192,  wstW + 1024);
      dma16(pwh0 + 12288,  wstW + 1536);
      f4v acc[2][2][4];
      #pragma unroll
      for (int ct = 0; ct < 2; ct++)
        #pragma unroll
        for (int rt = 0; rt < 2; rt++)
          #pragma unroll
          for (int g = 0; g < 4; g++) acc[ct][rt][g] = xp[ct][rt][g];
      #pragma unroll
      for (int r = 0; r < 16; r++){
        const int ct = r >> 3, kk = r & 7;
        if (r < 15){
          const int r2 = r + 1;
          const short* s = pwh0 + (r2 >> 3) * 16384 + (r2 & 7) * 512;
          short* d = wstW + ((r2 & 1) << 11);
          S_WAIT_LGKM0();
          dma16(s, d); dma16(s + 4096, d + 512);
          dma16(s + 8192, d + 1024); dma16(s + 12288, d + 1536);
          S_WAIT_VM4();
        } else {
          S_WAIT_VM0();
        }
        const short* bb = wstW + ((r & 1) << 11) + (lane << 3);
        const s8v B0 = *(const s8v*)(bb);
        const s8v B1 = *(const s8v*)(bb + 512);
        const s8v B2 = *(const s8v*)(bb + 1024);
        const s8v B3 = *(const s8v*)(bb + 1536);
        const s8v a0 = *(const s8v*)&h0in[ m16       * HSTR + kk * 32 + q * 8];
        const s8v a1 = *(const s8v*)&h0in[(16 + m16) * HSTR + kk * 32 + q * 8];
        acc[ct][0][0] = mfma16(a0, B0, acc[ct][0][0]);
        acc[ct][1][0] = mfma16(a1, B0, acc[ct][1][0]);
        acc[ct][0][1] = mfma16(a0, B1, acc[ct][0][1]);
        acc[ct][1][1] = mfma16(a1, B1, acc[ct][1][1]);
        acc[ct][0][2] = mfma16(a0, B2, acc[ct][0][2]);
        acc[ct][1][2] = mfma16(a1, B2, acc[ct][1][2]);
        acc[ct][0][3] = mfma16(a0, B3, acc[ct][0][3]);
        acc[ct][1][3] = mfma16(a1, B3, acc[ct][1][3]);
      }
      #pragma unroll
      for (int ct = 0; ct < 2; ct++)
        #pragma unroll
        for (int rt = 0; rt < 2; rt++)
          #pragma unroll
          for (int r = 0; r < 4; r++){
            float ii = sigm(acc[ct][rt][0][r]);
            float ff = sigm(acc[ct][rt][1][r]);
            float gg = tnh (acc[ct][rt][2][r]);
            float oo = sigm(acc[ct][rt][3][r]);
            c0[ct][rt][r] = ff * c0[ct][rt][r] + ii * gg;
            h0out[(rt * 16 + q * 4 + r) * HSTR + w * 32 + ct * 16 + m16] =
                f2bf(oo * tnh(c0[ct][rt][r]));
          }
    }
    __syncthreads();                             // (1) h0_new visible

    // ---- Phase B: gates1 = bias1 + h0_new@Wih1^T + h1_old@Whh1^T ----
    // 32 rounds, matrices interleaved (even r: Wih1/h0out, odd r: Whh1/h1in)
    {
      S_WAIT_LGKM0();
      dma16(pwi1,          wstW);
      dma16(pwi1 +  4096,  wstW +  512);
      dma16(pwi1 +  8192,  wstW + 1024);
      dma16(pwi1 + 12288,  wstW + 1536);
      f4v acc[2][2][4];
      #pragma unroll
      for (int ct = 0; ct < 2; ct++)
        #pragma unroll
        for (int rt = 0; rt < 2; rt++)
          #pragma unroll
          for (int g = 0; g < 4; g++){
            f4v tv = {bs1[ct][g], bs1[ct][g], bs1[ct][g], bs1[ct][g]};
            acc[ct][rt][g] = tv;
          }
      #pragma unroll
      for (int r = 0; r < 32; r++){
        const int ct = r >> 4, kk = (r >> 1) & 7, mat = r & 1;
        if (r < 31){
          const int r2 = r + 1;
          const short* s = ((r2 & 1) ? pwh1 : pwi1)
                           + (r2 >> 4) * 16384 + ((r2 >> 1) & 7) * 512;
          short* d = wstW + ((r2 & 1) << 11);
          S_WAIT_LGKM0();
          dma16(s, d); dma16(s + 4096, d + 512);
          dma16(s + 8192, d + 1024); dma16(s + 12288, d + 1536);
          S_WAIT_VM4();
        } else {
          S_WAIT_VM0();
        }
        const short* bb = wstW + ((r & 1) << 11) + (lane << 3);
        const s8v B0 = *(const s8v*)(bb);
        const s8v B1 = *(const s8v*)(bb + 512);
        const s8v B2 = *(const s8v*)(bb + 1024);
        const s8v B3 = *(const s8v*)(bb + 1536);
        const short* hA = mat ? h1in : h0out;
        const s8v a0 = *(const s8v*)&hA[ m16       * HSTR + kk * 32 + q * 8];
        const s8v a1 = *(const s8v*)&hA[(16 + m16) * HSTR + kk * 32 + q * 8];
        acc[ct][0][0] = mfma16(a0, B0, acc[ct][0][0]);
        acc[ct][1][0] = mfma16(a1, B0, acc[ct][1][0]);
        acc[ct][0][1] = mfma16(a0, B1, acc[ct][0][1]);
        acc[ct][1][1] = mfma16(a1, B1, acc[ct][1][1]);
        acc[ct][0][2] = mfma16(a0, B2, acc[ct][0][2]);
        acc[ct][1][2] = mfma16(a1, B2, acc[ct][1][2]);
        acc[ct][0][3] = mfma16(a0, B3, acc[ct][0][3]);
        acc[ct][1][3] = mfma16(a1, B3, acc[ct][1][3]);
      }
      #pragma unroll
      for (int ct = 0; ct < 2; ct++)
        #pragma unroll
        for (int rt = 0; rt < 2; rt++)
          #pragma unroll
          for (int r = 0; r < 4; r++){
            float ii = sigm(acc[ct][rt][0][r]);
            float ff = sigm(acc[ct][rt][1][r]);
            float gg = tnh (acc[ct][rt][2][r]);
            float oo = sigm(acc[ct][rt][3][r]);
            c1[ct][rt][r] = ff * c1[ct][rt][r] + ii * gg;
            h1out[(rt * 16 + q * 4 + r) * HSTR + w * 32 + ct * 16 + m16] =
                f2bf(oo * tnh(c1[ct][rt][r]));
          }
    }
    __syncthreads();                             // (2) h1_new visible

    // ---- Phase C: d = gelu(h1_new @ W3^T + b3), wave w -> cols w*16+m16 ----
    {
      S_WAIT_LGKM0();
      #pragma unroll
      for (int f = 0; f < 4; f++) dma16(pw3 + f * 512,       wstW + f * 512);
      #pragma unroll
      for (int f = 0; f < 4; f++) dma16(pw3 + (4 + f) * 512, wstW + 2048 + f * 512);
      S_WAIT_VM0();
      f4v ad0 = {b3c, b3c, b3c, b3c};
      f4v ad1 = ad0;
      #pragma unroll
      for (int f = 0; f < 8; f++){
        const s8v B = *(const s8v*)(wstW + (f >> 2) * 2048 + (f & 3) * 512 + (lane << 3));
        const s8v a0 = *(const s8v*)&h1out[ m16       * HSTR + f * 32 + q * 8];
        const s8v a1 = *(const s8v*)&h1out[(16 + m16) * HSTR + f * 32 + q * 8];
        ad0 = mfma16(a0, B, ad0);
        ad1 = mfma16(a1, B, ad1);
      }
      #pragma unroll
      for (int r = 0; r < 4; r++){
        dstg[( q * 4 + r)      * DSTR + w * 16 + m16] = f2bf(gelu(ad0[r]));
        dstg[(16 + q * 4 + r)  * DSTR + w * 16 + m16] = f2bf(gelu(ad1[r]));
      }
    }
    __syncthreads();                             // (3) d visible

    // ---- Phase D: out = d @ W4^T + b4 (waves 0,1; rt = w) ----
    if (w < 2){
      const int rt = w;
      f4v ao = {0.f, 0.f, 0.f, 0.f};
      #pragma unroll
      for (int kk = 0; kk < 4; kk++){
        const s8v bw = *(const s8v*)(pw4 + kk * 512);
        const s8v a  = *(const s8v*)&dstg[(rt * 16 + m16) * DSTR + kk * 32 + q * 8];
        ao = mfma16(a, bw, ao);
      }
      if (m16 < 2){
        #pragma unroll
        for (int r = 0; r < 4; r++)
          out[((size_t)(row0 + rt * 16 + q * 4 + r) * 256 + t) * 2 + m16] = ao[r] + b4v;
      }
    }
  }
}

extern "C" void kernel_launch(void* const* d_in, const int* in_sizes, int n_in,
                              void* d_out, int out_size, void* d_ws, size_t ws_size,
                              hipStream_t stream)
{
  const float* x    = (const float*)d_in[0];
  const float* W1   = (const float*)d_in[1];
  const float* b1   = (const float*)d_in[2];
  const float* g1   = (const float*)d_in[3];
  const float* be1  = (const float*)d_in[4];
  const float* W2   = (const float*)d_in[5];
  const float* b2   = (const float*)d_in[6];
  const float* g2   = (const float*)d_in[7];
  const float* be2  = (const float*)d_in[8];
  const float* Wih0 = (const float*)d_in[9];
  const float* Whh0 = (const float*)d_in[10];
  const float* bih0 = (const float*)d_in[11];
  const float* bhh0 = (const float*)d_in[12];
  const float* Wih1 = (const float*)d_in[13];
  const float* Whh1 = (const float*)d_in[14];
  const float* bih1 = (const float*)d_in[15];
  const float* bhh1 = (const float*)d_in[16];
  const float* W3   = (const float*)d_in[17];
  const float* b3   = (const float*)d_in[18];
  const float* W4   = (const float*)d_in[19];
  const float* b4   = (const float*)d_in[20];

  short* wsb = (short*)d_ws;

  prep_kernel<<<4232, 256, 0, stream>>>(Wih0, Whh0, Wih1, Whh1, W3, W4, wsb);
  curve_main<<<64, 512, 0, stream>>>(x, W1, b1, g1, be1, W2, b2, g2, be2,
                                     bih0, bhh0, bih1, bhh1, b3, b4, wsb,
                                     (float*)d_out);
}

// Round 9
// 14717.482 us; speedup vs baseline: 1.3378x; 1.3378x over previous
//
#include <hip/hip_runtime.h>
#include <math.h>

// ---------------------------------------------------------------------------
// CurvePredictor R9: R7 structure + double TLP (16 waves/CU).
// 64 blocks x 1024 threads (16 waves, 4/SIMD, VGPR=128 structural), 32 batch
// rows/block, weights L2-resident (proven R7: FETCH ~16MB). R8's DMA path
// regressed (lost L2 residency + 1-deep pipeline) -> reverted to VGPR loads.
// R7's 25.5us/step = ~10.7us TA-pull floor + exposed L2 latency; per-wave ILP
// is allocator-capped, so this round doubles wave-level parallelism instead:
// each wave owns a 16-col hidden slice (8-frag SSA load batches, 32 VGPRs),
// 16 waves interleave so load stalls overlap across waves (m114).
// Double-buffered h0/h1 in LDS, 3 barriers/step, zero cross-block sync.
// ---------------------------------------------------------------------------

typedef short s8v __attribute__((ext_vector_type(8)));   // 8 x bf16
typedef float f4v __attribute__((ext_vector_type(4)));   // 4 x f32

#define HSTR 264            // LDS h-row stride in shorts (33*16B)
#define DSTR 136

__device__ __forceinline__ f4v mfma16(s8v a, s8v b, f4v c){
  return __builtin_amdgcn_mfma_f32_16x16x32_bf16(a, b, c, 0, 0, 0);
}
__device__ __forceinline__ short f2bf(float f){
  unsigned u = __float_as_uint(f);
  u = u + 0x7FFFu + ((u >> 16) & 1u);
  return (short)(u >> 16);
}
__device__ __forceinline__ float wred(float v){
  #pragma unroll
  for (int o = 32; o; o >>= 1) v += __shfl_xor(v, o);
  return v;
}
__device__ __forceinline__ float sigm(float x){ return 1.0f / (1.0f + __expf(-x)); }
__device__ __forceinline__ float tnh(float x){
  x = fminf(15.0f, fmaxf(-15.0f, x));
  float e = __expf(2.0f * x);
  return (e - 1.0f) / (e + 1.0f);
}
__device__ __forceinline__ float gelu(float v){
  return 0.5f * v * (1.0f + erff(v * 0.70710678118654752440f));
}

// ws layout (shorts), swizzled for coalesced B-frag loads (same as R5-R8):
// main matrices (1024x256): elem = s*16384 + g*4096 + kk*512 + lane*8 + j
//   lane = q*16+m16, hid = s*16+m16, k = kk*32+q*8+j, gate-row = g*256+hid
//   [0,262144) Wih0  [262144,524288) Whh0  [524288,786432) Wih1  [786432,1048576) Whh1
// W3 [128][256]: 1048576 + s2*4096 + kk*512 + lane*8  (row = s2*16+m16)
// W4 padded [16][128]: 1081344 + kk*512 + lane*8      (row = m16, kk<4)
__global__ void prep_kernel(
    const float* __restrict__ Wih0, const float* __restrict__ Whh0,
    const float* __restrict__ Wih1, const float* __restrict__ Whh1,
    const float* __restrict__ W3,   const float* __restrict__ W4,
    short* __restrict__ wsb)
{
  const int i = blockIdx.x * 256 + threadIdx.x;
  if (i >= 1083392) return;
  float v;
  if (i < 1048576){
    const int seg = i >> 18;
    const int r   = i & 262143;
    const int s   = r >> 14;
    const int g   = (r >> 12) & 3;
    const int kk  = (r >> 9) & 7;
    const int q   = (r >> 7) & 3;
    const int m16 = (r >> 3) & 15;
    const int j   = r & 7;
    const int hid = s * 16 + m16;
    const int k   = kk * 32 + q * 8 + j;
    const float* mt = (seg == 0) ? Wih0 : (seg == 1) ? Whh0 : (seg == 2) ? Wih1 : Whh1;
    v = mt[(g * 256 + hid) * 256 + k];
  } else if (i < 1081344){
    const int r   = i - 1048576;
    const int s2  = r >> 12;
    const int kk  = (r >> 9) & 7;
    const int q   = (r >> 7) & 3;
    const int m16 = (r >> 3) & 15;
    const int j   = r & 7;
    v = W3[(s2 * 16 + m16) * 256 + kk * 32 + q * 8 + j];
  } else {
    const int r   = i - 1081344;
    const int kk  = (r >> 9) & 3;
    const int q   = (r >> 7) & 3;
    const int m16 = (r >> 3) & 15;
    const int j   = r & 7;
    const int k   = kk * 32 + q * 8 + j;
    v = (m16 < 2) ? W4[m16 * 128 + k] : 0.0f;
  }
  wsb[i] = f2bf(v);
}

// One matrix, this wave's 16-col slice, 32 batch rows, K=256.
// Four 8-frag SSA batches (2 kk x 4 gates each, 32 VGPRs), each consumed by
// 16 MFMAs. acc[rt][gate].
__device__ __forceinline__ void gemm16(
    const short* __restrict__ hA, const short* __restrict__ pw,
    int m16, int q, f4v (&acc)[2][4])
{
  #pragma unroll
  for (int half = 0; half < 4; half++){
    s8v B[8];
    #pragma unroll
    for (int f = 0; f < 8; f++)
      B[f] = *(const s8v*)(pw + (f & 3) * 4096 + (half * 2 + (f >> 2)) * 512);
    #pragma unroll
    for (int kx = 0; kx < 2; kx++){
      const int kk = half * 2 + kx;
      const s8v a0 = *(const s8v*)&hA[ m16       * HSTR + kk * 32 + q * 8];
      const s8v a1 = *(const s8v*)&hA[(16 + m16) * HSTR + kk * 32 + q * 8];
      #pragma unroll
      for (int g = 0; g < 4; g++){
        acc[0][g] = mfma16(a0, B[kx * 4 + g], acc[0][g]);
        acc[1][g] = mfma16(a1, B[kx * 4 + g], acc[1][g]);
      }
    }
  }
}

__global__ __launch_bounds__(1024, 1) void curve_main(
    const float* __restrict__ x,
    const float* __restrict__ W1, const float* __restrict__ b1,
    const float* __restrict__ g1, const float* __restrict__ be1,
    const float* __restrict__ W2, const float* __restrict__ b2,
    const float* __restrict__ g2, const float* __restrict__ be2,
    const float* __restrict__ bih0, const float* __restrict__ bhh0,
    const float* __restrict__ bih1, const float* __restrict__ bhh1,
    const float* __restrict__ b3, const float* __restrict__ b4,
    const short* __restrict__ wsb,
    float* __restrict__ out)
{
  const int tid  = threadIdx.x;
  const int w    = tid >> 6;        // wave 0..15 <-> 16-col hidden slice
  const int lane = tid & 63;
  const int q    = lane >> 4;
  const int m16  = lane & 15;
  const int row0 = blockIdx.x * 32;
  const int col  = w * 16 + m16;    // this lane's hidden column

  __shared__ __align__(16) short h0b[2][32 * HSTR];
  __shared__ __align__(16) short h1b[2][32 * HSTR];
  __shared__ __align__(16) short dstg[32 * DSTR];

  // --------- encoder: wave w computes batch rows row0 + u*16 + w -----------
  #pragma unroll 1
  for (int u = 0; u < 2; u++){
    const int rr = u * 16 + w;
    const int r  = row0 + rr;
    float xv[5];
    #pragma unroll
    for (int k = 0; k < 5; k++) xv[k] = x[r * 5 + k];
    float a0 = b1[lane], a1 = b1[lane + 64];
    #pragma unroll
    for (int k = 0; k < 5; k++){
      a0 += xv[k] * W1[lane * 5 + k];
      a1 += xv[k] * W1[(lane + 64) * 5 + k];
    }
    a0 = gelu(a0); a1 = gelu(a1);
    float mean = wred(a0 + a1) * (1.0f / 128.0f);
    float d0 = a0 - mean, d1 = a1 - mean;
    float inv = rsqrtf(wred(d0 * d0 + d1 * d1) * (1.0f / 128.0f) + 1e-5f);
    float y0 = d0 * inv * g1[lane]      + be1[lane];
    float y1 = d1 * inv * g1[lane + 64] + be1[lane + 64];

    float acc2[4];
    #pragma unroll
    for (int uu = 0; uu < 4; uu++) acc2[uu] = b2[lane + 64 * uu];
    for (int k = 0; k < 64; k++){
      float v0 = __shfl(y0, k);
      float v1 = __shfl(y1, k);
      #pragma unroll
      for (int uu = 0; uu < 4; uu++){
        const float* wr = W2 + (lane + 64 * uu) * 128;
        acc2[uu] += v0 * wr[k] + v1 * wr[k + 64];
      }
    }
    #pragma unroll
    for (int uu = 0; uu < 4; uu++) acc2[uu] = gelu(acc2[uu]);
    float s = acc2[0] + acc2[1] + acc2[2] + acc2[3];
    mean = wred(s) * (1.0f / 256.0f);
    float vv = 0.0f;
    #pragma unroll
    for (int uu = 0; uu < 4; uu++){ float d = acc2[uu] - mean; vv += d * d; }
    inv = rsqrtf(wred(vv) * (1.0f / 256.0f) + 1e-5f);
    #pragma unroll
    for (int uu = 0; uu < 4; uu++){
      int c = lane + 64 * uu;
      float e = (acc2[uu] - mean) * inv * g2[c] + be2[c];
      h0b[0][rr * HSTR + c] = f2bf(e);       // enc staged in h0 slot 0
    }
  }
  __syncthreads();

  // swizzled slice bases: wave w owns slice w; per-lane offset lane*16B
  const short* pwi0 = wsb            + w * 16384 + (lane << 3);
  const short* pwh0 = wsb +  262144  + w * 16384 + (lane << 3);
  const short* pwi1 = wsb +  524288  + w * 16384 + (lane << 3);
  const short* pwh1 = wsb +  786432  + w * 16384 + (lane << 3);
  const int    cg   = w & 7;         // decoder col-group
  const int    rtc  = w >> 3;        // decoder row-tile
  const short* pw3  = wsb + 1048576  + cg * 4096 + (lane << 3);
  const short* pw4  = wsb + 1081344  + (lane << 3);

  // ---- xp0 = enc @ Wih0_slice^T + (bih0+bhh0), kept in registers ----
  f4v xp[2][4];                     // [rt][gate]
  #pragma unroll
  for (int g = 0; g < 4; g++){
    const int n = g * 256 + col;
    const float bi = bih0[n] + bhh0[n];
    f4v t = {bi, bi, bi, bi};
    xp[0][g] = t; xp[1][g] = t;
  }
  gemm16(&h0b[0][0], pwi0, m16, q, xp);
  __syncthreads();
  for (int i = tid; i < 32 * HSTR; i += 1024){ h0b[0][i] = 0; h1b[0][i] = 0; }

  float bs1[4];
  #pragma unroll
  for (int g = 0; g < 4; g++){
    const int n = g * 256 + col;
    bs1[g] = bih1[n] + bhh1[n];
  }
  const float b3c = b3[cg * 16 + m16];
  const float b4v = (m16 < 2) ? b4[m16] : 0.0f;
  float c0[2][4], c1[2][4];         // [rt][r]
  #pragma unroll
  for (int rt = 0; rt < 2; rt++)
    #pragma unroll
    for (int r = 0; r < 4; r++){ c0[rt][r] = 0.f; c1[rt][r] = 0.f; }
  __syncthreads();

  // --------------------------- recurrence over T ---------------------------
  #pragma unroll 1
  for (int t = 0; t < 256; t++){
    const short* h0in  = h0b[t & 1];
    short*       h0out = h0b[(t + 1) & 1];
    const short* h1in  = h1b[t & 1];
    short*       h1out = h1b[(t + 1) & 1];

    // ---- A: gates0 = xp0 + h0_old @ Whh0^T -> c0, h0_new ----
    {
      f4v acc[2][4];
      #pragma unroll
      for (int rt = 0; rt < 2; rt++)
        #pragma unroll
        for (int g = 0; g < 4; g++) acc[rt][g] = xp[rt][g];
      gemm16(h0in, pwh0, m16, q, acc);
      #pragma unroll
      for (int rt = 0; rt < 2; rt++)
        #pragma unroll
        for (int r = 0; r < 4; r++){
          float ii = sigm(acc[rt][0][r]);
          float ff = sigm(acc[rt][1][r]);
          float gg = tnh (acc[rt][2][r]);
          float oo = sigm(acc[rt][3][r]);
          c0[rt][r] = ff * c0[rt][r] + ii * gg;
          h0out[(rt * 16 + q * 4 + r) * HSTR + col] = f2bf(oo * tnh(c0[rt][r]));
        }
    }
    __syncthreads();                             // (1) h0_new visible

    // ---- B: gates1 = bias1 + h0_new@Wih1^T + h1_old@Whh1^T -> c1, h1_new --
    {
      f4v acc[2][4];
      #pragma unroll
      for (int rt = 0; rt < 2; rt++)
        #pragma unroll
        for (int g = 0; g < 4; g++){
          f4v tv = {bs1[g], bs1[g], bs1[g], bs1[g]};
          acc[rt][g] = tv;
        }
      gemm16(h0out, pwi1, m16, q, acc);
      gemm16(h1in,  pwh1, m16, q, acc);
      #pragma unroll
      for (int rt = 0; rt < 2; rt++)
        #pragma unroll
        for (int r = 0; r < 4; r++){
          float ii = sigm(acc[rt][0][r]);
          float ff = sigm(acc[rt][1][r]);
          float gg = tnh (acc[rt][2][r]);
          float oo = sigm(acc[rt][3][r]);
          c1[rt][r] = ff * c1[rt][r] + ii * gg;
          h1out[(rt * 16 + q * 4 + r) * HSTR + col] = f2bf(oo * tnh(c1[rt][r]));
        }
    }
    __syncthreads();                             // (2) h1_new visible

    // ---- C: d = gelu(h1_new @ W3^T + b3); wave w -> cols cg*16, rows rtc*16
    {
      s8v B3[8];
      #pragma unroll
      for (int f = 0; f < 8; f++) B3[f] = *(const s8v*)(pw3 + f * 512);
      f4v ad = {b3c, b3c, b3c, b3c};
      #pragma unroll
      for (int kk = 0; kk < 8; kk++){
        const s8v a = *(const s8v*)&h1out[(rtc * 16 + m16) * HSTR + kk * 32 + q * 8];
        ad = mfma16(a, B3[kk], ad);
      }
      #pragma unroll
      for (int r = 0; r < 4; r++)
        dstg[(rtc * 16 + q * 4 + r) * DSTR + cg * 16 + m16] = f2bf(gelu(ad[r]));
    }
    __syncthreads();                             // (3) d visible

    // ---- D: out = d @ W4^T + b4 (waves 0,1; rt = w) ----
    if (w < 2){
      const int rt = w;
      f4v ao = {0.f, 0.f, 0.f, 0.f};
      #pragma unroll
      for (int kk = 0; kk < 4; kk++){
        const s8v bw = *(const s8v*)(pw4 + kk * 512);
        const s8v a  = *(const s8v*)&dstg[(rt * 16 + m16) * DSTR + kk * 32 + q * 8];
        ao = mfma16(a, bw, ao);
      }
      if (m16 < 2){
        #pragma unroll
        for (int r = 0; r < 4; r++)
          out[((size_t)(row0 + rt * 16 + q * 4 + r) * 256 + t) * 2 + m16] = ao[r] + b4v;
      }
    }
  }
}

extern "C" void kernel_launch(void* const* d_in, const int* in_sizes, int n_in,
                              void* d_out, int out_size, void* d_ws, size_t ws_size,
                              hipStream_t stream)
{
  const float* x    = (const float*)d_in[0];
  const float* W1   = (const float*)d_in[1];
  const float* b1   = (const float*)d_in[2];
  const float* g1   = (const float*)d_in[3];
  const float* be1  = (const float*)d_in[4];
  const float* W2   = (const float*)d_in[5];
  const float* b2   = (const float*)d_in[6];
  const float* g2   = (const float*)d_in[7];
  const float* be2  = (const float*)d_in[8];
  const float* Wih0 = (const float*)d_in[9];
  const float* Whh0 = (const float*)d_in[10];
  const float* bih0 = (const float*)d_in[11];
  const float* bhh0 = (const float*)d_in[12];
  const float* Wih1 = (const float*)d_in[13];
  const float* Whh1 = (const float*)d_in[14];
  const float* bih1 = (const float*)d_in[15];
  const float* bhh1 = (const float*)d_in[16];
  const float* W3   = (const float*)d_in[17];
  const float* b3   = (const float*)d_in[18];
  const float* W4   = (const float*)d_in[19];
  const float* b4   = (const float*)d_in[20];

  short* wsb = (short*)d_ws;

  prep_kernel<<<4232, 256, 0, stream>>>(Wih0, Whh0, Wih1, Whh1, W3, W4, wsb);
  curve_main<<<64, 1024, 0, stream>>>(x, W1, b1, g1, be1, W2, b2, g2, be2,
                                      bih0, bhh0, bih1, bhh1, b3, b4, wsb,
                                      (float*)d_out);
}

// Round 10
// 7247.420 us; speedup vs baseline: 2.7168x; 2.0307x over previous
//
#include <hip/hip_runtime.h>
#include <math.h>

// ---------------------------------------------------------------------------
// CurvePredictor R10: 256-thread blocks to unlock the VGPR budget.
// Allocator law (R1-R9): VGPR budget = 65536/blockDim -> 256 thr = ~256 regs
// (validated: R3 got 236). 64 blocks x 4 waves, 32 batch rows/block; wave w
// owns 4 hidden 16-col slices. Register state evicted to make room for TWO
// live 16-frag weight batches (128 VGPRs, double-buffered):
//   - xp (layer-0 input projection, f32) -> per-block d_ws region, streamed
//     back each step (bit-exact, +128KB/step to the L2-resident stream)
//   - c0/c1 cell state -> LDS (64 KB, tid-contiguous = conflict-free)
//   - W4 + decoder biases stay register-resident
// Weights pre-swizzled: every B-frag is one fully-coalesced 1KB wave load.
// Double-buffered h0/h1 in LDS, 3 barriers/step, zero cross-block sync.
// ---------------------------------------------------------------------------

typedef short s8v __attribute__((ext_vector_type(8)));   // 8 x bf16
typedef float f4v __attribute__((ext_vector_type(4)));   // 4 x f32

#define HSTR 264            // LDS h-row stride in shorts (33*16B)
#define DSTR 136
#define XP_OFF 2166784u     // byte offset of xp scratch in d_ws

__device__ __forceinline__ f4v mfma16(s8v a, s8v b, f4v c){
  return __builtin_amdgcn_mfma_f32_16x16x32_bf16(a, b, c, 0, 0, 0);
}
__device__ __forceinline__ short f2bf(float f){
  unsigned u = __float_as_uint(f);
  u = u + 0x7FFFu + ((u >> 16) & 1u);
  return (short)(u >> 16);
}
__device__ __forceinline__ float wred(float v){
  #pragma unroll
  for (int o = 32; o; o >>= 1) v += __shfl_xor(v, o);
  return v;
}
__device__ __forceinline__ float sigm(float x){ return 1.0f / (1.0f + __expf(-x)); }
__device__ __forceinline__ float tnh(float x){
  x = fminf(15.0f, fmaxf(-15.0f, x));
  float e = __expf(2.0f * x);
  return (e - 1.0f) / (e + 1.0f);
}
__device__ __forceinline__ float gelu(float v){
  return 0.5f * v * (1.0f + erff(v * 0.70710678118654752440f));
}

// ws layout (shorts), swizzled (same as R5-R9):
// main matrices (1024x256): elem = s*16384 + g*4096 + kk*512 + lane*8 + j
//   [0,262144) Wih0  [262144,524288) Whh0  [524288,786432) Wih1  [786432,1048576) Whh1
// W3 [128][256]: 1048576 + s2*4096 + kk*512 + lane*8
// W4 padded [16][128]: 1081344 + kk*512 + lane*8
// then at byte XP_OFF: f32 xp scratch, 128KB per block (64 blocks = 8MB).
__global__ void prep_kernel(
    const float* __restrict__ Wih0, const float* __restrict__ Whh0,
    const float* __restrict__ Wih1, const float* __restrict__ Whh1,
    const float* __restrict__ W3,   const float* __restrict__ W4,
    short* __restrict__ wsb)
{
  const int i = blockIdx.x * 256 + threadIdx.x;
  if (i >= 1083392) return;
  float v;
  if (i < 1048576){
    const int seg = i >> 18;
    const int r   = i & 262143;
    const int s   = r >> 14;
    const int g   = (r >> 12) & 3;
    const int kk  = (r >> 9) & 7;
    const int q   = (r >> 7) & 3;
    const int m16 = (r >> 3) & 15;
    const int j   = r & 7;
    const int hid = s * 16 + m16;
    const int k   = kk * 32 + q * 8 + j;
    const float* mt = (seg == 0) ? Wih0 : (seg == 1) ? Whh0 : (seg == 2) ? Wih1 : Whh1;
    v = mt[(g * 256 + hid) * 256 + k];
  } else if (i < 1081344){
    const int r   = i - 1048576;
    const int s2  = r >> 12;
    const int kk  = (r >> 9) & 7;
    const int q   = (r >> 7) & 3;
    const int m16 = (r >> 3) & 15;
    const int j   = r & 7;
    v = W3[(s2 * 16 + m16) * 256 + kk * 32 + q * 8 + j];
  } else {
    const int r   = i - 1081344;
    const int kk  = (r >> 9) & 3;
    const int q   = (r >> 7) & 3;
    const int m16 = (r >> 3) & 15;
    const int j   = r & 7;
    const int k   = kk * 32 + q * 8 + j;
    v = (m16 < 2) ? W4[m16 * 128 + k] : 0.0f;
  }
  wsb[i] = f2bf(v);
}

// Load one 16-frag half-batch (4 kk x 4 gates) into registers.
__device__ __forceinline__ void load16(s8v* B, const short* __restrict__ pw, int half){
  #pragma unroll
  for (int f = 0; f < 16; f++)
    B[f] = *(const s8v*)(pw + (f & 3) * 4096 + (half * 4 + (f >> 2)) * 512);
}
// Consume it: 32 MFMAs (2 row-tiles).
__device__ __forceinline__ void consume16(const s8v* B, const short* __restrict__ hA,
                                          int kk0, int m16, int q, f4v (&acc)[2][4]){
  #pragma unroll
  for (int kx = 0; kx < 4; kx++){
    const int kk = kk0 + kx;
    const s8v a0 = *(const s8v*)&hA[ m16       * HSTR + kk * 32 + q * 8];
    const s8v a1 = *(const s8v*)&hA[(16 + m16) * HSTR + kk * 32 + q * 8];
    #pragma unroll
    for (int g = 0; g < 4; g++){
      acc[0][g] = mfma16(a0, B[kx * 4 + g], acc[0][g]);
      acc[1][g] = mfma16(a1, B[kx * 4 + g], acc[1][g]);
    }
  }
}

__global__ __launch_bounds__(256, 1) void curve_main(
    const float* __restrict__ x,
    const float* __restrict__ W1, const float* __restrict__ b1,
    const float* __restrict__ g1, const float* __restrict__ be1,
    const float* __restrict__ W2, const float* __restrict__ b2,
    const float* __restrict__ g2, const float* __restrict__ be2,
    const float* __restrict__ bih0, const float* __restrict__ bhh0,
    const float* __restrict__ bih1, const float* __restrict__ bhh1,
    const float* __restrict__ b3, const float* __restrict__ b4,
    const short* __restrict__ wsb, float* __restrict__ xpg,
    float* __restrict__ out)
{
  const int tid  = threadIdx.x;
  const int w    = tid >> 6;        // wave 0..3, owns slices 4w..4w+3
  const int lane = tid & 63;
  const int q    = lane >> 4;
  const int m16  = lane & 15;
  const int row0 = blockIdx.x * 32;

  __shared__ __align__(16) short h0b[2][32 * HSTR];
  __shared__ __align__(16) short h1b[2][32 * HSTR];
  __shared__ __align__(16) short dstg[32 * DSTR];
  __shared__ __align__(16) float csh[64 * 256];   // c-state: idx*256 + tid

  // --------- encoder: wave w computes batch rows row0 + u*4 + w ------------
  #pragma unroll 1
  for (int u = 0; u < 8; u++){
    const int rr = u * 4 + w;
    const int r  = row0 + rr;
    float xv[5];
    #pragma unroll
    for (int k = 0; k < 5; k++) xv[k] = x[r * 5 + k];
    float a0 = b1[lane], a1 = b1[lane + 64];
    #pragma unroll
    for (int k = 0; k < 5; k++){
      a0 += xv[k] * W1[lane * 5 + k];
      a1 += xv[k] * W1[(lane + 64) * 5 + k];
    }
    a0 = gelu(a0); a1 = gelu(a1);
    float mean = wred(a0 + a1) * (1.0f / 128.0f);
    float d0 = a0 - mean, d1 = a1 - mean;
    float inv = rsqrtf(wred(d0 * d0 + d1 * d1) * (1.0f / 128.0f) + 1e-5f);
    float y0 = d0 * inv * g1[lane]      + be1[lane];
    float y1 = d1 * inv * g1[lane + 64] + be1[lane + 64];

    float acc2[4];
    #pragma unroll
    for (int uu = 0; uu < 4; uu++) acc2[uu] = b2[lane + 64 * uu];
    for (int k = 0; k < 64; k++){
      float v0 = __shfl(y0, k);
      float v1 = __shfl(y1, k);
      #pragma unroll
      for (int uu = 0; uu < 4; uu++){
        const float* wr = W2 + (lane + 64 * uu) * 128;
        acc2[uu] += v0 * wr[k] + v1 * wr[k + 64];
      }
    }
    #pragma unroll
    for (int uu = 0; uu < 4; uu++) acc2[uu] = gelu(acc2[uu]);
    float s = acc2[0] + acc2[1] + acc2[2] + acc2[3];
    mean = wred(s) * (1.0f / 256.0f);
    float vv = 0.0f;
    #pragma unroll
    for (int uu = 0; uu < 4; uu++){ float d = acc2[uu] - mean; vv += d * d; }
    inv = rsqrtf(wred(vv) * (1.0f / 256.0f) + 1e-5f);
    #pragma unroll
    for (int uu = 0; uu < 4; uu++){
      int c = lane + 64 * uu;
      float e = (acc2[uu] - mean) * inv * g2[c] + be2[c];
      h0b[0][rr * HSTR + c] = f2bf(e);       // enc staged in h0 slot 0
    }
  }
  __syncthreads();

  // swizzled bases for this wave (slice stride 16384 shorts), lane offset incl.
  const short* pwi0 = wsb            + (4 * w) * 16384 + (lane << 3);
  const short* pwh0 = wsb +  262144  + (4 * w) * 16384 + (lane << 3);
  const short* pwi1 = wsb +  524288  + (4 * w) * 16384 + (lane << 3);
  const short* pwh1 = wsb +  786432  + (4 * w) * 16384 + (lane << 3);
  const short* pw3  = wsb + 1048576  + (2 * w) * 4096 + (lane << 3);
  const short* pw4  = wsb + 1081344  + (lane << 3);
  float* xpw = xpg + blockIdx.x * 32768 + (4 * w) * 2048 + lane * 4;

  // ---- init: xp = enc @ Wih0^T + (bih0+bhh0) -> f32 scratch in d_ws ----
  #pragma unroll 1
  for (int s = 0; s < 4; s++){
    const short* pw = pwi0 + s * 16384;
    s8v P[16], Q[16];
    load16(P, pw, 0);
    load16(Q, pw, 1);
    f4v acc[2][4];
    #pragma unroll
    for (int g = 0; g < 4; g++){
      const int n = g * 256 + (4 * w + s) * 16 + m16;
      const float bi = bih0[n] + bhh0[n];
      f4v t = {bi, bi, bi, bi};
      acc[0][g] = t; acc[1][g] = t;
    }
    consume16(P, &h0b[0][0], 0, m16, q, acc);
    consume16(Q, &h0b[0][0], 4, m16, q, acc);
    float* xs = xpw + s * 2048;
    #pragma unroll
    for (int rt = 0; rt < 2; rt++)
      #pragma unroll
      for (int g = 0; g < 4; g++){
        float4 v4 = {acc[rt][g][0], acc[rt][g][1], acc[rt][g][2], acc[rt][g][3]};
        *(float4*)(xs + (rt * 4 + g) * 256) = v4;
      }
  }
  __syncthreads();
  for (int i = tid; i < 32 * HSTR; i += 256){ h0b[0][i] = 0; h1b[0][i] = 0; }
  for (int i = tid; i < 64 * 256; i += 256) csh[i] = 0.0f;

  // register-resident decoder constants
  s8v w4f[4];
  #pragma unroll
  for (int kk = 0; kk < 4; kk++) w4f[kk] = *(const s8v*)(pw4 + kk * 512);
  const float b3c0 = b3[(2 * w    ) * 16 + m16];
  const float b3c1 = b3[(2 * w + 1) * 16 + m16];
  const float b4v  = (m16 < 2) ? b4[m16] : 0.0f;
  __syncthreads();

  // --------------------------- recurrence over T ---------------------------
  #pragma unroll 1
  for (int t = 0; t < 256; t++){
    const short* h0in  = h0b[t & 1];
    short*       h0out = h0b[(t + 1) & 1];
    const short* h1in  = h1b[t & 1];
    short*       h1out = h1b[(t + 1) & 1];

    // ---- Phase A: gates0 = xp + h0_old @ Whh0^T -> c0 (LDS), h0_new ----
    #pragma unroll 1
    for (int s = 0; s < 4; s++){
      const short* pw = pwh0 + s * 16384;
      const float* xs = xpw + s * 2048;
      float4 xf[8];
      #pragma unroll
      for (int j = 0; j < 8; j++) xf[j] = *(const float4*)(xs + j * 256);
      s8v P[16], Q[16];
      load16(P, pw, 0);
      load16(Q, pw, 1);
      f4v acc[2][4];
      #pragma unroll
      for (int rt = 0; rt < 2; rt++)
        #pragma unroll
        for (int g = 0; g < 4; g++){
          const float4 v4 = xf[rt * 4 + g];
          f4v tv = {v4.x, v4.y, v4.z, v4.w};
          acc[rt][g] = tv;
        }
      consume16(P, h0in, 0, m16, q, acc);
      consume16(Q, h0in, 4, m16, q, acc);
      const int col = (4 * w + s) * 16 + m16;
      float* cp = &csh[(s * 8) * 256 + tid];
      #pragma unroll
      for (int rt = 0; rt < 2; rt++)
        #pragma unroll
        for (int r = 0; r < 4; r++){
          float cc = cp[(rt * 4 + r) * 256];
          float ii = sigm(acc[rt][0][r]);
          float ff = sigm(acc[rt][1][r]);
          float gg = tnh (acc[rt][2][r]);
          float oo = sigm(acc[rt][3][r]);
          cc = ff * cc + ii * gg;
          cp[(rt * 4 + r) * 256] = cc;
          h0out[(rt * 16 + q * 4 + r) * HSTR + col] = f2bf(oo * tnh(cc));
        }
    }
    __syncthreads();                             // (1) h0_new visible

    // ---- Phase B: gates1 = bias1 + h0_new@Wih1^T + h1_old@Whh1^T ----
    #pragma unroll 1
    for (int s = 0; s < 4; s++){
      const short* pi = pwi1 + s * 16384;
      const short* ph = pwh1 + s * 16384;
      const int col = (4 * w + s) * 16 + m16;
      s8v P[16], Q[16];
      load16(P, pi, 0);
      load16(Q, pi, 1);
      f4v acc[2][4];
      #pragma unroll
      for (int g = 0; g < 4; g++){
        const int n = g * 256 + col;
        const float bi = bih1[n] + bhh1[n];
        f4v tv = {bi, bi, bi, bi};
        acc[0][g] = tv; acc[1][g] = tv;
      }
      consume16(P, h0out, 0, m16, q, acc);
      load16(P, ph, 0);
      consume16(Q, h0out, 4, m16, q, acc);
      load16(Q, ph, 1);
      consume16(P, h1in, 0, m16, q, acc);
      consume16(Q, h1in, 4, m16, q, acc);
      float* cp = &csh[(32 + s * 8) * 256 + tid];
      #pragma unroll
      for (int rt = 0; rt < 2; rt++)
        #pragma unroll
        for (int r = 0; r < 4; r++){
          float cc = cp[(rt * 4 + r) * 256];
          float ii = sigm(acc[rt][0][r]);
          float ff = sigm(acc[rt][1][r]);
          float gg = tnh (acc[rt][2][r]);
          float oo = sigm(acc[rt][3][r]);
          cc = ff * cc + ii * gg;
          cp[(rt * 4 + r) * 256] = cc;
          h1out[(rt * 16 + q * 4 + r) * HSTR + col] = f2bf(oo * tnh(cc));
        }
    }
    __syncthreads();                             // (2) h1_new visible

    // ---- Phase C: d = gelu(h1_new @ W3^T + b3); wave w -> cgs {2w,2w+1} ----
    {
      s8v W3b[16];
      #pragma unroll
      for (int f = 0; f < 16; f++)
        W3b[f] = *(const s8v*)(pw3 + (f >> 3) * 4096 + (f & 7) * 512);
      #pragma unroll
      for (int cgi = 0; cgi < 2; cgi++){
        const float bc = cgi ? b3c1 : b3c0;
        #pragma unroll
        for (int rt = 0; rt < 2; rt++){
          f4v ad = {bc, bc, bc, bc};
          #pragma unroll
          for (int kk = 0; kk < 8; kk++){
            const s8v a = *(const s8v*)&h1out[(rt * 16 + m16) * HSTR + kk * 32 + q * 8];
            ad = mfma16(a, W3b[cgi * 8 + kk], ad);
          }
          #pragma unroll
          for (int r = 0; r < 4; r++)
            dstg[(rt * 16 + q * 4 + r) * DSTR + (2 * w + cgi) * 16 + m16] =
                f2bf(gelu(ad[r]));
        }
      }
    }
    __syncthreads();                             // (3) d visible

    // ---- Phase D: out = d @ W4^T + b4 (waves 0,1; rt = w) ----
    if (w < 2){
      const int rt = w;
      f4v ao = {0.f, 0.f, 0.f, 0.f};
      #pragma unroll
      for (int kk = 0; kk < 4; kk++){
        const s8v a = *(const s8v*)&dstg[(rt * 16 + m16) * DSTR + kk * 32 + q * 8];
        ao = mfma16(a, w4f[kk], ao);
      }
      if (m16 < 2){
        #pragma unroll
        for (int r = 0; r < 4; r++)
          out[((size_t)(row0 + rt * 16 + q * 4 + r) * 256 + t) * 2 + m16] = ao[r] + b4v;
      }
    }
  }
}

extern "C" void kernel_launch(void* const* d_in, const int* in_sizes, int n_in,
                              void* d_out, int out_size, void* d_ws, size_t ws_size,
                              hipStream_t stream)
{
  const float* x    = (const float*)d_in[0];
  const float* W1   = (const float*)d_in[1];
  const float* b1   = (const float*)d_in[2];
  const float* g1   = (const float*)d_in[3];
  const float* be1  = (const float*)d_in[4];
  const float* W2   = (const float*)d_in[5];
  const float* b2   = (const float*)d_in[6];
  const float* g2   = (const float*)d_in[7];
  const float* be2  = (const float*)d_in[8];
  const float* Wih0 = (const float*)d_in[9];
  const float* Whh0 = (const float*)d_in[10];
  const float* bih0 = (const float*)d_in[11];
  const float* bhh0 = (const float*)d_in[12];
  const float* Wih1 = (const float*)d_in[13];
  const float* Whh1 = (const float*)d_in[14];
  const float* bih1 = (const float*)d_in[15];
  const float* bhh1 = (const float*)d_in[16];
  const float* W3   = (const float*)d_in[17];
  const float* b3   = (const float*)d_in[18];
  const float* W4   = (const float*)d_in[19];
  const float* b4   = (const float*)d_in[20];

  short* wsb = (short*)d_ws;
  float* xpg = (float*)((char*)d_ws + XP_OFF);

  prep_kernel<<<4232, 256, 0, stream>>>(Wih0, Whh0, Wih1, Whh1, W3, W4, wsb);
  curve_main<<<64, 256, 0, stream>>>(x, W1, b1, g1, be1, W2, b2, g2, be2,
                                     bih0, bhh0, bih1, bhh1, b3, b4, wsb, xpg,
                                     (float*)d_out);
}